// Round 1
// baseline (226.052 us; speedup 1.0000x reference)
//
#include <hip/hip_runtime.h>
#include <hip/hip_bf16.h>
#include <math.h>

// KNRM fused kernel for MI355X (gfx950).
// B=256 batches, Q=32 query tokens, D=512 doc tokens, E=300 emb dim, K=11 kernels.
// One block per batch, 512 threads (8 waves).
//
// Numerics: kernel 0 (mu=1, sigma=1e-4) is an exact-token-match counter -> computed
// via integer compare (bf16 mm would fail threshold at matching pairs). Kernels 1..10
// (sigma=0.1) via bf16 MFMA cosine matmul with fp32 norm scales folded post-MFMA.

#define NB 256
#define NQ 32
#define ND 512
#define NE 300
#define NF4 75      // float4 per emb row
#define LROW 328    // LDS row stride in bf16 (656B = 16B aligned, 4-bank row offset)
#define CHUNK 64
#define NCHUNK 8
#define NT 512

typedef __bf16 bf16x8 __attribute__((ext_vector_type(8)));
typedef __bf16 bf16x4 __attribute__((ext_vector_type(4)));
typedef float f32x4 __attribute__((ext_vector_type(4)));

__global__ __launch_bounds__(NT, 1) void knrm_kernel(
    const int* __restrict__ qtok,
    const int* __restrict__ dtok,
    const float* __restrict__ emb,
    const float* __restrict__ fcw,
    const float* __restrict__ fcb,
    float* __restrict__ out)
{
  __shared__ __align__(16) __bf16 qlds[NQ][LROW];
  __shared__ __align__(16) __bf16 dlds[CHUNK][LROW];
  __shared__ float qscale[NQ];
  __shared__ float dscale[CHUNK];
  __shared__ float qk[NQ][11];
  __shared__ float red;

  const int b = blockIdx.x;
  const int t = threadIdx.x;
  const int lane = t & 63;
  const int w = t >> 6;

  // zero qk for k>=1 (k==0 is plain-stored by the match counter below)
  if (t < NQ * 11 && (t % 11) != 0) (&qk[0][0])[t] = 0.0f;
  if (t == 0) red = 0.0f;

  // ---- phase 1: query gather + norm scale + exact-match counts (kernel 0) ----
  {
    const int r = t >> 4;        // query row 0..31 (16 threads per row, same wave)
    const int j = t & 15;
    const int tq = qtok[b * NQ + r];
    const float4* rowp = (const float4*)(emb + (size_t)tq * NE);
    float ss = 0.0f;
    for (int c = j; c < NF4; c += 16) {
      float4 v = rowp[c];
      ss += v.x * v.x + v.y * v.y + v.z * v.z + v.w * v.w;
      bf16x4 h;
      h[0] = (__bf16)v.x; h[1] = (__bf16)v.y; h[2] = (__bf16)v.z; h[3] = (__bf16)v.w;
      *(bf16x4*)&qlds[r][4 * c] = h;
    }
    if (j < 5) {  // zero K-pad 300..319
      bf16x4 z = {(__bf16)0.0f, (__bf16)0.0f, (__bf16)0.0f, (__bf16)0.0f};
      *(bf16x4*)&qlds[r][NE + 4 * j] = z;
    }
    ss += __shfl_xor(ss, 1, 16);
    ss += __shfl_xor(ss, 2, 16);
    ss += __shfl_xor(ss, 4, 16);
    ss += __shfl_xor(ss, 8, 16);
    if (j == 0) qscale[r] = (tq > 0) ? 1.0f / (sqrtf(ss) + 1e-13f) : 0.0f;

    // kernel 0: count docs with identical (nonzero) token
    int cnt = 0;
    for (int jj = 0; jj < 32; ++jj) {
      int td = dtok[b * ND + j + 16 * jj];
      cnt += (tq > 0 && td == tq) ? 1 : 0;
    }
    cnt += __shfl_xor(cnt, 1, 16);
    cnt += __shfl_xor(cnt, 2, 16);
    cnt += __shfl_xor(cnt, 4, 16);
    cnt += __shfl_xor(cnt, 8, 16);
    if (j == 0) qk[r][0] = (float)cnt;
  }

  // ---- per-wave MFMA tile assignment ----
  const int mt = w >> 2;       // m-tile 0/1 (q rows 16mt..16mt+15)
  const int nt = w & 3;        // n-tile 0..3 (docs 16nt..16nt+15 within chunk)
  const int l15 = lane & 15;
  const int l4 = lane >> 4;

  float rbfacc[4][10];
  #pragma unroll
  for (int r4 = 0; r4 < 4; ++r4)
    #pragma unroll
    for (int k = 0; k < 10; ++k) rbfacc[r4][k] = 0.0f;

  const __bf16* aptr = &qlds[mt * 16 + l15][l4 * 8];
  const __bf16* bptr = &dlds[nt * 16 + l15][l4 * 8];

  const float muk[10] = {0.9f, 0.7f, 0.5f, 0.3f, 0.1f,
                         -0.1f, -0.3f, -0.5f, -0.7f, -0.9f};

  for (int ch = 0; ch < NCHUNK; ++ch) {
    __syncthreads();  // prior MFMA reads of dlds done (and phase-1 writes visible)
    {
      const int r = t >> 3;    // doc row 0..63 (8 threads per row, same wave)
      const int j = t & 7;
      const int td = dtok[b * ND + ch * CHUNK + r];
      const float4* rowp = (const float4*)(emb + (size_t)td * NE);
      float ss = 0.0f;
      for (int c = j; c < NF4; c += 8) {
        float4 v = rowp[c];
        ss += v.x * v.x + v.y * v.y + v.z * v.z + v.w * v.w;
        bf16x4 h;
        h[0] = (__bf16)v.x; h[1] = (__bf16)v.y; h[2] = (__bf16)v.z; h[3] = (__bf16)v.w;
        *(bf16x4*)&dlds[r][4 * c] = h;
      }
      if (j < 5) {  // zero K-pad 300..319
        bf16x4 z = {(__bf16)0.0f, (__bf16)0.0f, (__bf16)0.0f, (__bf16)0.0f};
        *(bf16x4*)&dlds[r][NE + 4 * j] = z;
      }
      ss += __shfl_xor(ss, 1, 8);
      ss += __shfl_xor(ss, 2, 8);
      ss += __shfl_xor(ss, 4, 8);
      if (j == 0) dscale[r] = (td > 0) ? 1.0f / (sqrtf(ss) + 1e-13f) : 0.0f;
    }
    __syncthreads();

    // MFMA: mm tile (16x16) for this wave, K=320 in 10 steps
    f32x4 acc = {0.0f, 0.0f, 0.0f, 0.0f};
    #pragma unroll
    for (int k = 0; k < 10; ++k) {
      bf16x8 av = *(const bf16x8*)(aptr + k * 32);
      bf16x8 bv = *(const bf16x8*)(bptr + k * 32);
      acc = __builtin_amdgcn_mfma_f32_16x16x32_bf16(av, bv, acc, 0, 0, 0);
    }

    // RBF accumulate (kernels 1..10). C/D layout: col=lane&15 (doc), row=(lane>>4)*4+reg (q).
    const float ds = dscale[nt * 16 + l15];
    #pragma unroll
    for (int r4 = 0; r4 < 4; ++r4) {
      const float qs = qscale[mt * 16 + l4 * 4 + r4];
      const float s = qs * ds;
      // masked pair -> mm huge -> all rbf underflow to exact 0 (matches rbf*mask)
      const float mm = (s == 0.0f) ? 1e8f : acc[r4] * s;
      #pragma unroll
      for (int k = 0; k < 10; ++k) {
        float d = mm - muk[k];
        // exp(-d^2 * 50) = exp2(d^2 * -50/ln2)
        rbfacc[r4][k] += __builtin_amdgcn_exp2f(d * d * -72.13475204444817f);
      }
    }
  }

  // reduce rbfacc over the 16 doc-columns of this wave's tile, add into qk
  #pragma unroll
  for (int r4 = 0; r4 < 4; ++r4) {
    #pragma unroll
    for (int k = 0; k < 10; ++k) {
      float v = rbfacc[r4][k];
      v += __shfl_xor(v, 1, 16);
      v += __shfl_xor(v, 2, 16);
      v += __shfl_xor(v, 4, 16);
      v += __shfl_xor(v, 8, 16);
      if (l15 == 0) atomicAdd(&qk[mt * 16 + l4 * 4 + r4][k + 1], v);
    }
  }
  __syncthreads();

  // ---- epilogue: score_b = sum_{q,k} log(max(qk,1e-10))*0.01*fc_w[k] + fc_b ----
  float v = 0.0f;
  if (t < NQ * 11) {
    int q = t / 11;
    int k = t % 11;
    v = logf(fmaxf(qk[q][k], 1e-10f)) * 0.01f * fcw[k];
  }
  #pragma unroll
  for (int off = 1; off < 64; off <<= 1) v += __shfl_xor(v, off, 64);
  if (lane == 0) atomicAdd(&red, v);
  __syncthreads();
  if (t == 0) out[b] = red + fcb[0];
}

extern "C" void kernel_launch(void* const* d_in, const int* in_sizes, int n_in,
                              void* d_out, int out_size, void* d_ws, size_t ws_size,
                              hipStream_t stream) {
  const int* qtok = (const int*)d_in[0];
  const int* dtok = (const int*)d_in[1];
  const float* emb = (const float*)d_in[2];
  const float* fcw = (const float*)d_in[3];
  const float* fcb = (const float*)d_in[4];
  float* out = (float*)d_out;
  knrm_kernel<<<NB, NT, 0, stream>>>(qtok, dtok, emb, fcw, fcb, out);
}